// Round 4
// baseline (4571.055 us; speedup 1.0000x reference)
//
#include <hip/hip_runtime.h>
#include <cstdint>
#include <cstddef>

#define U_CNT 100000
#define I_CNT 50000
#define D_DIM 64
#define N_CNT (U_CNT + I_CNT)
#define NNZ_CNT 4000000
#define EPS_F 0.2f

// Bucket-major CSR: key = (col/CHUNK)*N + row. Per phase, a block's edges are
// one contiguous range; all co-resident blocks sweep buckets together so the
// 2.4MB x-window per phase fits each XCD's 4MiB L2.
#define NB 16
#define CHUNK ((N_CNT + NB - 1) / NB)                    // 9375 cols = 2.4 MB of x
#define M_CNT (N_CNT * NB)                               // 2,400,000 keys
#define SCAN_TILE 1024
#define N_TILES2 ((M_CNT + SCAN_TILE - 1) / SCAN_TILE)   // 2344
#define ROWS_PER_BLK 98                                  // 98*64*4B = 25,088B LDS -> 6 blocks/CU
#define G_LAYER ((N_CNT + ROWS_PER_BLK - 1) / ROWS_PER_BLK)  // 1531 blocks (co-resident)
#define COL_MASK 0x3FFFF                                 // col < 150000 < 2^18

// ---------------- CSR build: histogram over bucket-major keys ----------------
__global__ void hist_kernel(const int* __restrict__ rows, const int* __restrict__ cols,
                            int* __restrict__ deg) {
    int t = blockIdx.x * blockDim.x + threadIdx.x;
    if (t >= NNZ_CNT / 4) return;
    int4 r4 = ((const int4*)rows)[t];
    int4 c4 = ((const int4*)cols)[t];
    atomicAdd(&deg[(c4.x / CHUNK) * N_CNT + r4.x], 1);
    atomicAdd(&deg[(c4.y / CHUNK) * N_CNT + r4.y], 1);
    atomicAdd(&deg[(c4.z / CHUNK) * N_CNT + r4.z], 1);
    atomicAdd(&deg[(c4.w / CHUNK) * N_CNT + r4.w], 1);
}

// ---------------- scan stage 1: per-tile scan ----------------
// Writes tile-local exclusive scan into BOTH rowptr and deg (deg becomes the
// scatter cursor, pre-seeded with start offsets -> scatter needs no rowptr read).
__global__ __launch_bounds__(256) void partial_scan_kernel(
    int* __restrict__ deg, int* __restrict__ rowptr, int* __restrict__ tileSums) {
    __shared__ int lds[256];
    const int t = threadIdx.x;
    const int gbase = blockIdx.x * SCAN_TILE + t * 4;
    int v[4];
    int s = 0;
    #pragma unroll
    for (int j = 0; j < 4; ++j) {
        int i = gbase + j;
        v[j] = (i < M_CNT) ? deg[i] : 0;
        s += v[j];
    }
    lds[t] = s;
    __syncthreads();
    for (int off = 1; off < 256; off <<= 1) {
        int x = (t >= off) ? lds[t - off] : 0;
        __syncthreads();
        lds[t] += x;
        __syncthreads();
    }
    int ex = (t > 0) ? lds[t - 1] : 0;
    #pragma unroll
    for (int j = 0; j < 4; ++j) {
        int i = gbase + j;
        if (i < M_CNT) { rowptr[i] = ex; deg[i] = ex; }
        ex += v[j];
    }
    if (t == 255) tileSums[blockIdx.x] = lds[255];
}

// ---------------- scan stage 2: scan tile sums (2344, single block) ----------
__global__ __launch_bounds__(256) void scan_sums_kernel(
    const int* __restrict__ tileSums, int* __restrict__ tileOffs,
    int* __restrict__ rowptr) {
    __shared__ int lds[256];
    const int t = threadIdx.x;
    int carry = 0;
    for (int base = 0; base < N_TILES2; base += SCAN_TILE) {
        int v[4];
        int s = 0;
        #pragma unroll
        for (int j = 0; j < 4; ++j) {
            int i = base + t * 4 + j;
            v[j] = (i < N_TILES2) ? tileSums[i] : 0;
            s += v[j];
        }
        lds[t] = s;
        __syncthreads();
        for (int off = 1; off < 256; off <<= 1) {
            int x = (t >= off) ? lds[t - off] : 0;
            __syncthreads();
            lds[t] += x;
            __syncthreads();
        }
        int ex = carry + ((t > 0) ? lds[t - 1] : 0);
        #pragma unroll
        for (int j = 0; j < 4; ++j) {
            int i = base + t * 4 + j;
            if (i < N_TILES2) tileOffs[i] = ex;
            ex += v[j];
        }
        carry += lds[255];
        __syncthreads();
    }
    if (t == 0) rowptr[M_CNT] = carry;
}

// ---------------- scan stage 3: add tile offsets to rowptr AND cursor --------
__global__ __launch_bounds__(256) void add_offs_kernel(
    int* __restrict__ rowptr, int* __restrict__ deg, const int* __restrict__ tileOffs) {
    const int off = tileOffs[blockIdx.x];
    const int gbase = blockIdx.x * SCAN_TILE + threadIdx.x * 4;
    #pragma unroll
    for (int j = 0; j < 4; ++j) {
        int i = gbase + j;
        if (i < M_CNT) { rowptr[i] += off; deg[i] += off; }
    }
}

// ---------------- CSR build: scatter (col|rlocal<<18, val) -------------------
__global__ void scatter_kernel(const int* __restrict__ rows, const int* __restrict__ cols,
                               const float* __restrict__ vals,
                               int* __restrict__ cursor, int2* __restrict__ cpack) {
    int t = blockIdx.x * blockDim.x + threadIdx.x;
    if (t >= NNZ_CNT / 4) return;
    int4   r4 = ((const int4*)rows)[t];
    int4   c4 = ((const int4*)cols)[t];
    float4 v4 = ((const float4*)vals)[t];
    int k, p, rl;
    k = (c4.x / CHUNK) * N_CNT + r4.x; rl = r4.x % ROWS_PER_BLK;
    p = atomicAdd(&cursor[k], 1); cpack[p] = make_int2(c4.x | (rl << 18), __float_as_int(v4.x));
    k = (c4.y / CHUNK) * N_CNT + r4.y; rl = r4.y % ROWS_PER_BLK;
    p = atomicAdd(&cursor[k], 1); cpack[p] = make_int2(c4.y | (rl << 18), __float_as_int(v4.y));
    k = (c4.z / CHUNK) * N_CNT + r4.z; rl = r4.z % ROWS_PER_BLK;
    p = atomicAdd(&cursor[k], 1); cpack[p] = make_int2(c4.z | (rl << 18), __float_as_int(v4.z));
    k = (c4.w / CHUNK) * N_CNT + r4.w; rl = r4.w % ROWS_PER_BLK;
    p = atomicAdd(&cursor[k], 1); cpack[p] = make_int2(c4.w | (rl << 18), __float_as_int(v4.w));
}

__device__ __forceinline__ float sgnf(float x) {
    return (x > 0.f) ? 1.f : ((x < 0.f) ? -1.f : 0.f);
}

// ---------------- edge-parallel phase-swept SpMM layer -------------
// Block owns 98 rows, acc[98][64] f32 in LDS. Per phase, the block's edges are
// one contiguous cpack range; 16-lane groups stride over it uniformly (no
// divergence, no per-segment rowptr loads) and ds_add_f32 into LDS acc.
// 1531 blocks x 25KiB LDS = 6 blocks/CU everywhere -> co-resident lockstep.
// MODE 0: gather (ue,ie) split; xnext = ego; acc_out = ego
// MODE 1: gather xin;          xnext = ego; acc_out += ego
// MODE 2: gather xin;          acc_out = (acc_out + ego)/3
template <int MODE>
__global__ __launch_bounds__(256, 6) void layer_edge_kernel(
    const int* __restrict__ rowptr, const int2* __restrict__ cpack,
    const float4* __restrict__ xin, const float4* __restrict__ ue4,
    const float4* __restrict__ ie4,
    const float4* __restrict__ noise_k, float4* __restrict__ xnext,
    float4* __restrict__ acc_out) {
    const int row0 = blockIdx.x * ROWS_PER_BLK;
    if (row0 >= N_CNT) return;
    const int nrows = (N_CNT - row0 < ROWS_PER_BLK) ? (N_CNT - row0) : ROWS_PER_BLK;

    __shared__ float acc[ROWS_PER_BLK * D_DIM];   // 25,088 B
    for (int i = threadIdx.x; i < ROWS_PER_BLK * D_DIM; i += 256) acc[i] = 0.f;
    __syncthreads();

    const int g  = threadIdx.x >> 4;   // edge-group 0..15
    const int gl = threadIdx.x & 15;   // lane in group: owns float4 of D

    for (int ph = 0; ph < NB; ++ph) {
        const int b0 = ph * N_CNT + row0;
        const int E0 = rowptr[b0];
        const int E1 = rowptr[b0 + nrows];
        #pragma unroll 2
        for (int e = E0 + g; e < E1; e += 16) {
            int2 p = cpack[e];                          // group-uniform 8B load
            float vj = __int_as_float(p.y);
            int col = p.x & COL_MASK;
            int rl  = ((unsigned)p.x) >> 18;
            const float4* xb;
            if (MODE == 0) {
                xb = (col < U_CNT) ? (ue4 + (size_t)col * 16)
                                   : (ie4 + (size_t)(col - U_CNT) * 16);
            } else {
                xb = xin + (size_t)col * 16;
            }
            float4 xr = xb[gl];                         // 256B/row over 16 lanes
            float* ap = &acc[rl * D_DIM + gl * 4];
            atomicAdd(ap + 0, vj * xr.x);               // ds_add_f32
            atomicAdd(ap + 1, vj * xr.y);
            atomicAdd(ap + 2, vj * xr.z);
            atomicAdd(ap + 3, vj * xr.w);
        }
        __syncthreads();   // phase lockstep (correctness never depends on it)
    }

    // epilogue: noise + outputs; group g handles rows g, g+16, ...
    for (int rl = g; rl < nrows; rl += 16) {
        const int r = row0 + rl;
        float4 a = *(const float4*)&acc[rl * D_DIM + gl * 4];
        float4 nz = noise_k[(size_t)r * 16 + gl];
        float sq = nz.x * nz.x + nz.y * nz.y + nz.z * nz.z + nz.w * nz.w;
        #pragma unroll
        for (int off = 8; off > 0; off >>= 1) sq += __shfl_xor(sq, off);
        float inv = EPS_F / fmaxf(sqrtf(sq), 1e-12f);

        float4 ego;
        ego.x = a.x + sgnf(a.x) * nz.x * inv;
        ego.y = a.y + sgnf(a.y) * nz.y * inv;
        ego.z = a.z + sgnf(a.z) * nz.z * inv;
        ego.w = a.w + sgnf(a.w) * nz.w * inv;

        size_t oi = (size_t)r * 16 + gl;
        if (MODE == 0) {
            xnext[oi] = ego;
            acc_out[oi] = ego;
        } else if (MODE == 1) {
            xnext[oi] = ego;
            float4 o = acc_out[oi];
            o.x += ego.x; o.y += ego.y; o.z += ego.z; o.w += ego.w;
            acc_out[oi] = o;
        } else {
            float4 o = acc_out[oi];
            o.x = (o.x + ego.x) * (1.f / 3.f);
            o.y = (o.y + ego.y) * (1.f / 3.f);
            o.z = (o.z + ego.z) * (1.f / 3.f);
            o.w = (o.w + ego.w) * (1.f / 3.f);
            acc_out[oi] = o;
        }
    }
}

extern "C" void kernel_launch(void* const* d_in, const int* in_sizes, int n_in,
                              void* d_out, int out_size, void* d_ws, size_t ws_size,
                              hipStream_t stream) {
    const float* ue    = (const float*)d_in[0];
    const float* ie    = (const float*)d_in[1];
    const int*   rows  = (const int*)d_in[2];
    const int*   cols  = (const int*)d_in[3];
    const float* vals  = (const float*)d_in[4];
    const float* noise = (const float*)d_in[5];
    float* out = (float*)d_out;
    char*  ws  = (char*)d_ws;

    auto align16 = [](size_t x) { return (x + 15) & ~(size_t)15; };
    size_t off = 0;
    int*   rowptr2  = (int*)(ws + off);  off = align16(off + (size_t)(M_CNT + 1) * 4);
    int*   tileSums = (int*)(ws + off);  off = align16(off + (size_t)N_TILES2 * 4);
    int*   tileOffs = (int*)(ws + off);  off = align16(off + (size_t)N_TILES2 * 4);
    int2*  cpack    = (int2*)(ws + off); off = align16(off + (size_t)NNZ_CNT * 8);
    float* bufA     = (float*)(ws + off); off += (size_t)N_CNT * D_DIM * 4;
    // deg/cursor (9.6 MB) aliases bufA: build completes before layer 1 writes bufA.
    int*   deg2     = (int*)bufA;
    (void)ws_size; (void)in_sizes; (void)n_in; (void)out_size;

    const size_t ND = (size_t)N_CNT * D_DIM;
    float* cl = out + ND;  // ego_cl region; doubles as layer-0 output / layer-1 input

    // ---- CSR build (bucket-major keys, cursor pre-seeded by scan) ----
    hipMemsetAsync(deg2, 0, (size_t)M_CNT * 4, stream);
    hist_kernel<<<(NNZ_CNT / 4 + 255) / 256, 256, 0, stream>>>(rows, cols, deg2);
    partial_scan_kernel<<<N_TILES2, 256, 0, stream>>>(deg2, rowptr2, tileSums);
    scan_sums_kernel<<<1, 256, 0, stream>>>(tileSums, tileOffs, rowptr2);
    add_offs_kernel<<<N_TILES2, 256, 0, stream>>>(rowptr2, deg2, tileOffs);
    scatter_kernel<<<(NNZ_CNT / 4 + 255) / 256, 256, 0, stream>>>(rows, cols, vals,
                                                                  deg2, cpack);

    // ---- 3 edge-parallel phase-swept propagation layers ----
    layer_edge_kernel<0><<<G_LAYER, 256, 0, stream>>>(
        rowptr2, cpack, nullptr, (const float4*)ue, (const float4*)ie,
        (const float4*)(noise + 0 * ND), (float4*)cl, (float4*)out);
    layer_edge_kernel<1><<<G_LAYER, 256, 0, stream>>>(
        rowptr2, cpack, (const float4*)cl, nullptr, nullptr,
        (const float4*)(noise + 1 * ND), (float4*)bufA, (float4*)out);
    layer_edge_kernel<2><<<G_LAYER, 256, 0, stream>>>(
        rowptr2, cpack, (const float4*)bufA, nullptr, nullptr,
        (const float4*)(noise + 2 * ND), nullptr, (float4*)out);
}

// Round 5
// 4526.525 us; speedup vs baseline: 1.0098x; 1.0098x over previous
//
#include <hip/hip_runtime.h>
#include <cstdint>
#include <cstddef>

#define U_CNT 100000
#define I_CNT 50000
#define D_DIM 64
#define N_CNT (U_CNT + I_CNT)
#define NNZ_CNT 4000000
#define EPS_F 0.2f

// Bucket-major CSR: key = (col/CHUNK)*N + row. Per phase, a block's edges are
// one contiguous range; all co-resident blocks sweep buckets together so the
// 2.4MB x-window per phase fits each XCD's 4MiB L2.
#define NB 16
#define CHUNK ((N_CNT + NB - 1) / NB)                    // 9375 cols = 2.4 MB of x
#define M_CNT (N_CNT * NB)                               // 2,400,000 keys
#define SCAN_TILE 1024
#define N_TILES2 ((M_CNT + SCAN_TILE - 1) / SCAN_TILE)   // 2344
#define ROWS_PER_BLK 98
#define R_STRIDE 65                                      // floats; 65%32==1 decorrelates banks
#define G_LAYER ((N_CNT + ROWS_PER_BLK - 1) / ROWS_PER_BLK)  // 1531 blocks (co-resident)
#define COL_MASK 0x3FFFF                                 // col < 150000 < 2^18

// ---------------- CSR build: histogram over bucket-major keys ----------------
__global__ void hist_kernel(const int* __restrict__ rows, const int* __restrict__ cols,
                            int* __restrict__ deg) {
    int t = blockIdx.x * blockDim.x + threadIdx.x;
    if (t >= NNZ_CNT / 4) return;
    int4 r4 = ((const int4*)rows)[t];
    int4 c4 = ((const int4*)cols)[t];
    atomicAdd(&deg[(c4.x / CHUNK) * N_CNT + r4.x], 1);
    atomicAdd(&deg[(c4.y / CHUNK) * N_CNT + r4.y], 1);
    atomicAdd(&deg[(c4.z / CHUNK) * N_CNT + r4.z], 1);
    atomicAdd(&deg[(c4.w / CHUNK) * N_CNT + r4.w], 1);
}

// ---------------- scan stage 1: per-tile local scan ----------------
// Tile-local exclusive scan into BOTH rowptr and deg (deg becomes the scatter
// cursor, pre-seeded with tile-LOCAL start offsets; tile offsets added on the
// fly by scatter/layer -> no add_offs pass).
__global__ __launch_bounds__(256) void partial_scan_kernel(
    int* __restrict__ deg, int* __restrict__ rowptr, int* __restrict__ tileSums) {
    __shared__ int lds[256];
    const int t = threadIdx.x;
    const int gbase = blockIdx.x * SCAN_TILE + t * 4;
    int v[4];
    int s = 0;
    #pragma unroll
    for (int j = 0; j < 4; ++j) {
        int i = gbase + j;
        v[j] = (i < M_CNT) ? deg[i] : 0;
        s += v[j];
    }
    lds[t] = s;
    __syncthreads();
    for (int off = 1; off < 256; off <<= 1) {
        int x = (t >= off) ? lds[t - off] : 0;
        __syncthreads();
        lds[t] += x;
        __syncthreads();
    }
    int ex = (t > 0) ? lds[t - 1] : 0;
    #pragma unroll
    for (int j = 0; j < 4; ++j) {
        int i = gbase + j;
        if (i < M_CNT) { rowptr[i] = ex; deg[i] = ex; }
        ex += v[j];
    }
    if (t == 255) tileSums[blockIdx.x] = lds[255];
}

// ---------------- scan stage 2: scan tile sums (2344, single block) ----------
__global__ __launch_bounds__(256) void scan_sums_kernel(
    const int* __restrict__ tileSums, int* __restrict__ tileOffs,
    int* __restrict__ rowptr) {
    __shared__ int lds[256];
    const int t = threadIdx.x;
    int carry = 0;
    for (int base = 0; base < N_TILES2; base += SCAN_TILE) {
        int v[4];
        int s = 0;
        #pragma unroll
        for (int j = 0; j < 4; ++j) {
            int i = base + t * 4 + j;
            v[j] = (i < N_TILES2) ? tileSums[i] : 0;
            s += v[j];
        }
        lds[t] = s;
        __syncthreads();
        for (int off = 1; off < 256; off <<= 1) {
            int x = (t >= off) ? lds[t - off] : 0;
            __syncthreads();
            lds[t] += x;
            __syncthreads();
        }
        int ex = carry + ((t > 0) ? lds[t - 1] : 0);
        #pragma unroll
        for (int j = 0; j < 4; ++j) {
            int i = base + t * 4 + j;
            if (i < N_TILES2) tileOffs[i] = ex;
            ex += v[j];
        }
        carry += lds[255];
        __syncthreads();
    }
    if (t == 0) rowptr[M_CNT] = carry;
}

// ---------------- CSR build: scatter (col|rlocal<<18, val) -------------------
// cursor holds tile-local scan; absolute position = cursor + tileOffs[k>>10].
__global__ void scatter_kernel(const int* __restrict__ rows, const int* __restrict__ cols,
                               const float* __restrict__ vals,
                               int* __restrict__ cursor, const int* __restrict__ tileOffs,
                               int2* __restrict__ cpack) {
    int t = blockIdx.x * blockDim.x + threadIdx.x;
    if (t >= NNZ_CNT / 4) return;
    int4   r4 = ((const int4*)rows)[t];
    int4   c4 = ((const int4*)cols)[t];
    float4 v4 = ((const float4*)vals)[t];
    int k, p, rl;
    k = (c4.x / CHUNK) * N_CNT + r4.x; rl = r4.x % ROWS_PER_BLK;
    p = atomicAdd(&cursor[k], 1) + tileOffs[k >> 10];
    cpack[p] = make_int2(c4.x | (rl << 18), __float_as_int(v4.x));
    k = (c4.y / CHUNK) * N_CNT + r4.y; rl = r4.y % ROWS_PER_BLK;
    p = atomicAdd(&cursor[k], 1) + tileOffs[k >> 10];
    cpack[p] = make_int2(c4.y | (rl << 18), __float_as_int(v4.y));
    k = (c4.z / CHUNK) * N_CNT + r4.z; rl = r4.z % ROWS_PER_BLK;
    p = atomicAdd(&cursor[k], 1) + tileOffs[k >> 10];
    cpack[p] = make_int2(c4.z | (rl << 18), __float_as_int(v4.z));
    k = (c4.w / CHUNK) * N_CNT + r4.w; rl = r4.w % ROWS_PER_BLK;
    p = atomicAdd(&cursor[k], 1) + tileOffs[k >> 10];
    cpack[p] = make_int2(c4.w | (rl << 18), __float_as_int(v4.w));
}

__device__ __forceinline__ float sgnf(float x) {
    return (x > 0.f) ? 1.f : ((x < 0.f) ? -1.f : 0.f);
}

// ---------------- edge-parallel phase-swept SpMM layer -------------
// Block owns 98 rows; acc layout [row][comp][lane] stride 65 in LDS (sole
// shared object -> LDS offset 0; stride 65 decorrelates ds_add bank windows).
// Accumulation via raw fire-and-forget ds_add_f32 (native fp LDS atomic; HIP's
// atomicAdd lowers to a CAS loop, which was round 4's 6x collapse).
// Explicit s_waitcnt lgkmcnt(0) before each barrier drains the hand-issued DS
// ops the compiler can't see.
// MODE 0: gather (ue,ie) split; xnext = ego; acc_out = ego
// MODE 1: gather xin;          xnext = ego; acc_out += ego
// MODE 2: gather xin;          acc_out = (acc_out + ego)/3
template <int MODE>
__global__ __launch_bounds__(256, 6) void layer_edge_kernel(
    const int* __restrict__ rowptr, const int* __restrict__ tileOffs,
    const int2* __restrict__ cpack,
    const float4* __restrict__ xin, const float4* __restrict__ ue4,
    const float4* __restrict__ ie4,
    const float4* __restrict__ noise_k, float4* __restrict__ xnext,
    float4* __restrict__ acc_out) {
    const int row0 = blockIdx.x * ROWS_PER_BLK;
    if (row0 >= N_CNT) return;
    const int nrows = (N_CNT - row0 < ROWS_PER_BLK) ? (N_CNT - row0) : ROWS_PER_BLK;

    __shared__ float acc[ROWS_PER_BLK * R_STRIDE];   // 25,480 B, sole LDS object
    for (int i = threadIdx.x; i < ROWS_PER_BLK * R_STRIDE; i += 256) acc[i] = 0.f;
    __syncthreads();

    const int g  = threadIdx.x >> 4;   // edge-group 0..15
    const int gl = threadIdx.x & 15;   // lane in group: owns float4 of D

    for (int ph = 0; ph < NB; ++ph) {
        const int i0 = ph * N_CNT + row0;
        const int i1 = i0 + nrows;
        const int E0 = rowptr[i0] + tileOffs[i0 >> 10];
        const int E1 = (i1 == M_CNT) ? NNZ_CNT : (rowptr[i1] + tileOffs[i1 >> 10]);
        #pragma unroll 4
        for (int e = E0 + g; e < E1; e += 16) {
            int2 p = cpack[e];                          // group-uniform 8B load
            float vj = __int_as_float(p.y);
            int col = p.x & COL_MASK;
            int rl  = ((unsigned)p.x) >> 18;
            const float4* xb;
            if (MODE == 0) {
                xb = (col < U_CNT) ? (ue4 + (size_t)col * 16)
                                   : (ie4 + (size_t)(col - U_CNT) * 16);
            } else {
                xb = xin + (size_t)col * 16;
            }
            float4 xr = xb[gl];                         // 256B/row over 16 lanes
            unsigned ao = (unsigned)((rl * R_STRIDE + gl) * 4);   // byte offset, comp stride 64B
            asm volatile("ds_add_f32 %0, %1"            :: "v"(ao), "v"(vj * xr.x));
            asm volatile("ds_add_f32 %0, %1 offset:64"  :: "v"(ao), "v"(vj * xr.y));
            asm volatile("ds_add_f32 %0, %1 offset:128" :: "v"(ao), "v"(vj * xr.z));
            asm volatile("ds_add_f32 %0, %1 offset:192" :: "v"(ao), "v"(vj * xr.w));
        }
        asm volatile("s_waitcnt lgkmcnt(0)");   // drain hand-issued DS ops
        __syncthreads();                        // phase lockstep + cross-wave visibility
    }

    // epilogue: noise + outputs; group g handles rows g, g+16, ...
    for (int rl = g; rl < nrows; rl += 16) {
        const int r = row0 + rl;
        float4 a;
        a.x = acc[rl * R_STRIDE +  0 + gl];
        a.y = acc[rl * R_STRIDE + 16 + gl];
        a.z = acc[rl * R_STRIDE + 32 + gl];
        a.w = acc[rl * R_STRIDE + 48 + gl];
        float4 nz = noise_k[(size_t)r * 16 + gl];
        float sq = nz.x * nz.x + nz.y * nz.y + nz.z * nz.z + nz.w * nz.w;
        #pragma unroll
        for (int off = 8; off > 0; off >>= 1) sq += __shfl_xor(sq, off);
        float inv = EPS_F / fmaxf(sqrtf(sq), 1e-12f);

        float4 ego;
        ego.x = a.x + sgnf(a.x) * nz.x * inv;
        ego.y = a.y + sgnf(a.y) * nz.y * inv;
        ego.z = a.z + sgnf(a.z) * nz.z * inv;
        ego.w = a.w + sgnf(a.w) * nz.w * inv;

        size_t oi = (size_t)r * 16 + gl;
        if (MODE == 0) {
            xnext[oi] = ego;
            acc_out[oi] = ego;
        } else if (MODE == 1) {
            xnext[oi] = ego;
            float4 o = acc_out[oi];
            o.x += ego.x; o.y += ego.y; o.z += ego.z; o.w += ego.w;
            acc_out[oi] = o;
        } else {
            float4 o = acc_out[oi];
            o.x = (o.x + ego.x) * (1.f / 3.f);
            o.y = (o.y + ego.y) * (1.f / 3.f);
            o.z = (o.z + ego.z) * (1.f / 3.f);
            o.w = (o.w + ego.w) * (1.f / 3.f);
            acc_out[oi] = o;
        }
    }
}

extern "C" void kernel_launch(void* const* d_in, const int* in_sizes, int n_in,
                              void* d_out, int out_size, void* d_ws, size_t ws_size,
                              hipStream_t stream) {
    const float* ue    = (const float*)d_in[0];
    const float* ie    = (const float*)d_in[1];
    const int*   rows  = (const int*)d_in[2];
    const int*   cols  = (const int*)d_in[3];
    const float* vals  = (const float*)d_in[4];
    const float* noise = (const float*)d_in[5];
    float* out = (float*)d_out;
    char*  ws  = (char*)d_ws;

    auto align16 = [](size_t x) { return (x + 15) & ~(size_t)15; };
    size_t off = 0;
    int*   rowptr2  = (int*)(ws + off);  off = align16(off + (size_t)(M_CNT + 1) * 4);
    int*   tileSums = (int*)(ws + off);  off = align16(off + (size_t)N_TILES2 * 4);
    int*   tileOffs = (int*)(ws + off);  off = align16(off + (size_t)N_TILES2 * 4);
    int2*  cpack    = (int2*)(ws + off); off = align16(off + (size_t)NNZ_CNT * 8);
    float* bufA     = (float*)(ws + off); off += (size_t)N_CNT * D_DIM * 4;
    // deg/cursor (9.6 MB) aliases bufA: build completes before layer 1 writes bufA.
    int*   deg2     = (int*)bufA;
    (void)ws_size; (void)in_sizes; (void)n_in; (void)out_size;

    const size_t ND = (size_t)N_CNT * D_DIM;
    float* cl = out + ND;  // ego_cl region; doubles as layer-0 output / layer-1 input

    // ---- CSR build (bucket-major keys; tile offsets folded in at use sites) ----
    hipMemsetAsync(deg2, 0, (size_t)M_CNT * 4, stream);
    hist_kernel<<<(NNZ_CNT / 4 + 255) / 256, 256, 0, stream>>>(rows, cols, deg2);
    partial_scan_kernel<<<N_TILES2, 256, 0, stream>>>(deg2, rowptr2, tileSums);
    scan_sums_kernel<<<1, 256, 0, stream>>>(tileSums, tileOffs, rowptr2);
    scatter_kernel<<<(NNZ_CNT / 4 + 255) / 256, 256, 0, stream>>>(rows, cols, vals,
                                                                  deg2, tileOffs, cpack);

    // ---- 3 edge-parallel phase-swept propagation layers ----
    layer_edge_kernel<0><<<G_LAYER, 256, 0, stream>>>(
        rowptr2, tileOffs, cpack, nullptr, (const float4*)ue, (const float4*)ie,
        (const float4*)(noise + 0 * ND), (float4*)cl, (float4*)out);
    layer_edge_kernel<1><<<G_LAYER, 256, 0, stream>>>(
        rowptr2, tileOffs, cpack, (const float4*)cl, nullptr, nullptr,
        (const float4*)(noise + 1 * ND), (float4*)bufA, (float4*)out);
    layer_edge_kernel<2><<<G_LAYER, 256, 0, stream>>>(
        rowptr2, tileOffs, cpack, (const float4*)bufA, nullptr, nullptr,
        (const float4*)(noise + 2 * ND), nullptr, (float4*)out);
}

// Round 7
// 1239.583 us; speedup vs baseline: 3.6876x; 3.6517x over previous
//
#include <hip/hip_runtime.h>
#include <cstdint>
#include <cstddef>

#define U_CNT 100000
#define I_CNT 50000
#define D_DIM 64
#define N_CNT (U_CNT + I_CNT)
#define NNZ_CNT 4000000
#define EPS_F 0.2f
#define SCAN_TILE 1024
#define N_TILES ((N_CNT + SCAN_TILE - 1) / SCAN_TILE)   // 147

typedef float v4f __attribute__((ext_vector_type(4)));

// ---------------- CSR build: histogram (4 edges/thread) ----------------
__global__ void hist_kernel(const int* __restrict__ rows, int* __restrict__ deg) {
    int t = blockIdx.x * blockDim.x + threadIdx.x;
    if (t >= NNZ_CNT / 4) return;
    int4 r4 = ((const int4*)rows)[t];
    atomicAdd(&deg[r4.x], 1);
    atomicAdd(&deg[r4.y], 1);
    atomicAdd(&deg[r4.z], 1);
    atomicAdd(&deg[r4.w], 1);
}

// ---------------- scan stage 1: per-tile scan ----------------
// Tile-local exclusive scan into BOTH rowptr and deg; after add_offs, deg is
// the absolute scatter cursor (scatter then needs no rowptr read).
__global__ __launch_bounds__(256) void partial_scan_kernel(
    int* __restrict__ deg, int* __restrict__ rowptr, int* __restrict__ tileSums) {
    __shared__ int lds[256];
    const int t = threadIdx.x;
    const int gbase = blockIdx.x * SCAN_TILE + t * 4;
    int v[4];
    int s = 0;
    #pragma unroll
    for (int j = 0; j < 4; ++j) {
        int i = gbase + j;
        v[j] = (i < N_CNT) ? deg[i] : 0;
        s += v[j];
    }
    lds[t] = s;
    __syncthreads();
    for (int off = 1; off < 256; off <<= 1) {
        int x = (t >= off) ? lds[t - off] : 0;
        __syncthreads();
        lds[t] += x;
        __syncthreads();
    }
    int ex = (t > 0) ? lds[t - 1] : 0;
    #pragma unroll
    for (int j = 0; j < 4; ++j) {
        int i = gbase + j;
        if (i < N_CNT) { rowptr[i] = ex; deg[i] = ex; }
        ex += v[j];
    }
    if (t == 255) tileSums[blockIdx.x] = lds[255];
}

// ---------------- scan stage 2: scan tile sums (147 <= 256) ----------------
__global__ __launch_bounds__(256) void scan_sums_kernel(
    const int* __restrict__ tileSums, int* __restrict__ tileOffs,
    int* __restrict__ rowptr) {
    __shared__ int lds[256];
    const int t = threadIdx.x;
    lds[t] = (t < N_TILES) ? tileSums[t] : 0;
    __syncthreads();
    for (int off = 1; off < 256; off <<= 1) {
        int x = (t >= off) ? lds[t - off] : 0;
        __syncthreads();
        lds[t] += x;
        __syncthreads();
    }
    if (t < N_TILES) tileOffs[t] = (t > 0) ? lds[t - 1] : 0;
    if (t == 255) rowptr[N_CNT] = lds[255];
}

// ---------------- scan stage 3: add tile offsets to rowptr AND cursor --------
__global__ __launch_bounds__(256) void add_offs_kernel(
    int* __restrict__ rowptr, int* __restrict__ deg, const int* __restrict__ tileOffs) {
    const int off = tileOffs[blockIdx.x];
    const int gbase = blockIdx.x * SCAN_TILE + threadIdx.x * 4;
    #pragma unroll
    for (int j = 0; j < 4; ++j) {
        int i = gbase + j;
        if (i < N_CNT) { rowptr[i] += off; deg[i] += off; }
    }
}

// ---------------- CSR build: scatter via pre-seeded cursor ----------------
// One atomic per edge (cursor holds absolute start offsets; no rowptr read).
__global__ void scatter_kernel(const int* __restrict__ rows, const int* __restrict__ cols,
                               const float* __restrict__ vals,
                               int* __restrict__ cursor, int2* __restrict__ cpack) {
    int t = blockIdx.x * blockDim.x + threadIdx.x;
    if (t >= NNZ_CNT / 4) return;
    int4   r4 = ((const int4*)rows)[t];
    int4   c4 = ((const int4*)cols)[t];
    float4 v4 = ((const float4*)vals)[t];
    int p;
    p = atomicAdd(&cursor[r4.x], 1); cpack[p] = make_int2(c4.x, __float_as_int(v4.x));
    p = atomicAdd(&cursor[r4.y], 1); cpack[p] = make_int2(c4.y, __float_as_int(v4.y));
    p = atomicAdd(&cursor[r4.z], 1); cpack[p] = make_int2(c4.z, __float_as_int(v4.z));
    p = atomicAdd(&cursor[r4.w], 1); cpack[p] = make_int2(c4.w, __float_as_int(v4.w));
}

__device__ __forceinline__ float sgnf(float x) {
    return (x > 0.f) ? 1.f : ((x < 0.f) ? -1.f : 0.f);
}

// ---------------- fused SpMM + noise + accumulate ----------------
// Round-0 proven structure: 16 lanes per row (lane owns a float4 of D=64);
// 4 rows/wave, 16 rows per 256-thread block. NEW: streaming operands (cpack,
// noise, outputs) use non-temporal loads/stores so L2 capacity is reserved
// for the randomly-gathered x table (the only operand with reuse).
// MODE 0: gather from (ue,ie) split; xnext = ego; acc_out = ego   (layer 0)
// MODE 1: gather from xin;          xnext = ego; acc_out += ego   (layer 1)
// MODE 2: gather from xin;          acc_out = (acc_out + ego)/3   (layer 2)
template <int MODE>
__global__ __launch_bounds__(256) void layer_kernel(
    const int* __restrict__ rowptr, const int2* __restrict__ cpack,
    const v4f* __restrict__ xin, const v4f* __restrict__ ue4,
    const v4f* __restrict__ ie4,
    const v4f* __restrict__ noise_k, v4f* __restrict__ xnext,
    v4f* __restrict__ acc_out) {
    const int gl = threadIdx.x & 15;                 // lane within 16-lane row group
    const int r  = blockIdx.x * 16 + (threadIdx.x >> 4);
    if (r >= N_CNT) return;
    const int start = rowptr[r];
    const int end   = rowptr[r + 1];

    // hoisted streaming noise load (independent of edge loop; issues early)
    v4f nz = __builtin_nontemporal_load(&noise_k[(size_t)r * 16 + gl]);

    v4f acc = {0.f, 0.f, 0.f, 0.f};
    #pragma unroll 4
    for (int e = start; e < end; ++e) {
        // group-uniform 8B streaming metadata load (non-temporal: read once)
        unsigned long long pv = __builtin_nontemporal_load(
            (const unsigned long long*)(cpack + e));
        int   col = (int)(unsigned)(pv & 0xffffffffu);
        float vj  = __int_as_float((int)(unsigned)(pv >> 32));
        const v4f* xb;
        if (MODE == 0) {
            xb = (col < U_CNT) ? (ue4 + (size_t)col * 16)
                               : (ie4 + (size_t)(col - U_CNT) * 16);
        } else {
            xb = xin + (size_t)col * 16;
        }
        v4f xr = xb[gl];            // gather: NORMAL load (wants L2 residency)
        acc += vj * xr;
    }

    // normalized noise (norm over the row's 64 features = 16 lanes x 4 comps)
    float sq = nz.x * nz.x + nz.y * nz.y + nz.z * nz.z + nz.w * nz.w;
    #pragma unroll
    for (int off = 8; off > 0; off >>= 1) sq += __shfl_xor(sq, off);
    float inv = EPS_F / fmaxf(sqrtf(sq), 1e-12f);

    v4f ego;
    ego.x = acc.x + sgnf(acc.x) * nz.x * inv;
    ego.y = acc.y + sgnf(acc.y) * nz.y * inv;
    ego.z = acc.z + sgnf(acc.z) * nz.z * inv;
    ego.w = acc.w + sgnf(acc.w) * nz.w * inv;

    size_t oi = (size_t)r * 16 + gl;
    if (MODE == 0) {
        __builtin_nontemporal_store(ego, &xnext[oi]);
        __builtin_nontemporal_store(ego, &acc_out[oi]);
    } else if (MODE == 1) {
        __builtin_nontemporal_store(ego, &xnext[oi]);
        v4f o = __builtin_nontemporal_load(&acc_out[oi]);
        o += ego;
        __builtin_nontemporal_store(o, &acc_out[oi]);
    } else {
        v4f o = __builtin_nontemporal_load(&acc_out[oi]);
        o = (o + ego) * (1.f / 3.f);
        __builtin_nontemporal_store(o, &acc_out[oi]);
    }
}

extern "C" void kernel_launch(void* const* d_in, const int* in_sizes, int n_in,
                              void* d_out, int out_size, void* d_ws, size_t ws_size,
                              hipStream_t stream) {
    const float* ue    = (const float*)d_in[0];
    const float* ie    = (const float*)d_in[1];
    const int*   rows  = (const int*)d_in[2];
    const int*   cols  = (const int*)d_in[3];
    const float* vals  = (const float*)d_in[4];
    const float* noise = (const float*)d_in[5];
    float* out = (float*)d_out;
    char*  ws  = (char*)d_ws;

    auto align16 = [](size_t x) { return (x + 15) & ~(size_t)15; };
    size_t off = 0;
    int*   rowptr   = (int*)(ws + off);  off = align16(off + (size_t)(N_CNT + 1) * 4);
    int*   deg      = (int*)(ws + off);  off = align16(off + (size_t)N_CNT * 4);
    int*   tileSums = (int*)(ws + off);  off = align16(off + (size_t)N_TILES * 4);
    int*   tileOffs = (int*)(ws + off);  off = align16(off + (size_t)N_TILES * 4);
    int2*  cpack    = (int2*)(ws + off); off = align16(off + (size_t)NNZ_CNT * 8);
    float* bufA     = (float*)(ws + off); off += (size_t)N_CNT * D_DIM * 4;
    (void)ws_size; (void)in_sizes; (void)n_in; (void)out_size;

    const size_t ND = (size_t)N_CNT * D_DIM;
    float* cl = out + ND;  // ego_cl region; doubles as layer-0 output / layer-1 input

    // ---- CSR build (cursor pre-seeded by scan; scatter = 1 atomic/edge) ----
    hipMemsetAsync(deg, 0, (size_t)N_CNT * 4, stream);
    hist_kernel<<<(NNZ_CNT / 4 + 255) / 256, 256, 0, stream>>>(rows, deg);
    partial_scan_kernel<<<N_TILES, 256, 0, stream>>>(deg, rowptr, tileSums);
    scan_sums_kernel<<<1, 256, 0, stream>>>(tileSums, tileOffs, rowptr);
    add_offs_kernel<<<N_TILES, 256, 0, stream>>>(rowptr, deg, tileOffs);
    scatter_kernel<<<(NNZ_CNT / 4 + 255) / 256, 256, 0, stream>>>(rows, cols, vals,
                                                                  deg, cpack);

    // ---- 3 propagation layers (fused spmm + noise + accumulate) ----
    int blocks = (N_CNT + 15) / 16;
    layer_kernel<0><<<blocks, 256, 0, stream>>>(rowptr, cpack, nullptr,
                                                (const v4f*)ue, (const v4f*)ie,
                                                (const v4f*)(noise + 0 * ND),
                                                (v4f*)cl, (v4f*)out);
    layer_kernel<1><<<blocks, 256, 0, stream>>>(rowptr, cpack, (const v4f*)cl,
                                                nullptr, nullptr,
                                                (const v4f*)(noise + 1 * ND),
                                                (v4f*)bufA, (v4f*)out);
    layer_kernel<2><<<blocks, 256, 0, stream>>>(rowptr, cpack, (const v4f*)bufA,
                                                nullptr, nullptr,
                                                (const v4f*)(noise + 2 * ND),
                                                nullptr, (v4f*)out);
}

// Round 8
// 1105.047 us; speedup vs baseline: 4.1365x; 1.1217x over previous
//
#include <hip/hip_runtime.h>
#include <cstdint>
#include <cstddef>

#define U_CNT 100000
#define I_CNT 50000
#define D_DIM 64
#define N_CNT (U_CNT + I_CNT)
#define NNZ_CNT 4000000
#define EPS_F 0.2f
#define SCAN_TILE 1024
#define N_TILES ((N_CNT + SCAN_TILE - 1) / SCAN_TILE)   // 147

typedef float v4f __attribute__((ext_vector_type(4)));

// ---------------- CSR build: histogram (4 edges/thread) ----------------
__global__ void hist_kernel(const int* __restrict__ rows, int* __restrict__ deg) {
    int t = blockIdx.x * blockDim.x + threadIdx.x;
    if (t >= NNZ_CNT / 4) return;
    int4 r4 = ((const int4*)rows)[t];
    atomicAdd(&deg[r4.x], 1);
    atomicAdd(&deg[r4.y], 1);
    atomicAdd(&deg[r4.z], 1);
    atomicAdd(&deg[r4.w], 1);
}

// ---------------- hierarchical scan, stage 1: per-tile scan ----------------
// Scans deg into rowptr (tile-local exclusive), writes tile total, and ZEROES
// deg so it can be reused as the scatter cursor.  (round-0 proven form)
__global__ __launch_bounds__(256) void partial_scan_kernel(
    int* __restrict__ deg, int* __restrict__ rowptr, int* __restrict__ tileSums) {
    __shared__ int lds[256];
    const int t = threadIdx.x;
    const int gbase = blockIdx.x * SCAN_TILE + t * 4;
    int v[4];
    int s = 0;
    #pragma unroll
    for (int j = 0; j < 4; ++j) {
        int i = gbase + j;
        v[j] = (i < N_CNT) ? deg[i] : 0;
        if (i < N_CNT) deg[i] = 0;
        s += v[j];
    }
    lds[t] = s;
    __syncthreads();
    for (int off = 1; off < 256; off <<= 1) {
        int x = (t >= off) ? lds[t - off] : 0;
        __syncthreads();
        lds[t] += x;
        __syncthreads();
    }
    int ex = (t > 0) ? lds[t - 1] : 0;
    #pragma unroll
    for (int j = 0; j < 4; ++j) {
        int i = gbase + j;
        if (i < N_CNT) rowptr[i] = ex;
        ex += v[j];
    }
    if (t == 255) tileSums[blockIdx.x] = lds[255];
}

// ---------------- stage 2: scan tile sums (147 <= 256) ----------------
__global__ __launch_bounds__(256) void scan_sums_kernel(
    const int* __restrict__ tileSums, int* __restrict__ tileOffs,
    int* __restrict__ rowptr) {
    __shared__ int lds[256];
    const int t = threadIdx.x;
    lds[t] = (t < N_TILES) ? tileSums[t] : 0;
    __syncthreads();
    for (int off = 1; off < 256; off <<= 1) {
        int x = (t >= off) ? lds[t - off] : 0;
        __syncthreads();
        lds[t] += x;
        __syncthreads();
    }
    if (t < N_TILES) tileOffs[t] = (t > 0) ? lds[t - 1] : 0;
    if (t == 255) rowptr[N_CNT] = lds[255];
}

// ---------------- stage 3: add tile offsets ----------------
__global__ __launch_bounds__(256) void add_offs_kernel(
    int* __restrict__ rowptr, const int* __restrict__ tileOffs) {
    const int off = tileOffs[blockIdx.x];
    const int gbase = blockIdx.x * SCAN_TILE + threadIdx.x * 4;
    #pragma unroll
    for (int j = 0; j < 4; ++j) {
        int i = gbase + j;
        if (i < N_CNT) rowptr[i] += off;
    }
}

// ---------------- CSR build: scatter packed (col,val), 4 edges/thread ------
// (round-0 proven form: rowptr read + zero-seeded cursor)
__global__ void scatter_kernel(const int* __restrict__ rows, const int* __restrict__ cols,
                               const float* __restrict__ vals,
                               const int* __restrict__ rowptr, int* __restrict__ cursor,
                               int2* __restrict__ cpack) {
    int t = blockIdx.x * blockDim.x + threadIdx.x;
    if (t >= NNZ_CNT / 4) return;
    int4   r4 = ((const int4*)rows)[t];
    int4   c4 = ((const int4*)cols)[t];
    float4 v4 = ((const float4*)vals)[t];
    int p;
    p = rowptr[r4.x] + atomicAdd(&cursor[r4.x], 1); cpack[p] = make_int2(c4.x, __float_as_int(v4.x));
    p = rowptr[r4.y] + atomicAdd(&cursor[r4.y], 1); cpack[p] = make_int2(c4.y, __float_as_int(v4.y));
    p = rowptr[r4.z] + atomicAdd(&cursor[r4.z], 1); cpack[p] = make_int2(c4.z, __float_as_int(v4.z));
    p = rowptr[r4.w] + atomicAdd(&cursor[r4.w], 1); cpack[p] = make_int2(c4.w, __float_as_int(v4.w));
}

__device__ __forceinline__ float sgnf(float x) {
    return (x > 0.f) ? 1.f : ((x < 0.f) ? -1.f : 0.f);
}

// ---------------- fused SpMM + noise + accumulate ----------------
// Round-0 proven structure: 16 lanes per row (lane owns a float4 of D=64);
// 4 rows/wave, 16 rows per 256-thread block.
// vs round 0: (i) noise loaded non-temporal and hoisted (single-use stream),
// (ii) cpack loaded non-temporal (stream within the layer; won't survive to
// the next layer anyway), (iii) edge loop unroll 8 for more gather lines in
// flight (counters: 46% HBM, 10% VALU, 75% occ -> queue-depth limited).
// All stores NORMAL: xnext/acc_out are gathered by the next layer (L2 reuse).
// MODE 0: gather from (ue,ie) split; xnext = ego; acc_out = ego   (layer 0)
// MODE 1: gather from xin;          xnext = ego; acc_out += ego   (layer 1)
// MODE 2: gather from xin;          acc_out = (acc_out + ego)/3   (layer 2)
template <int MODE>
__global__ __launch_bounds__(256) void layer_kernel(
    const int* __restrict__ rowptr, const int2* __restrict__ cpack,
    const v4f* __restrict__ xin, const v4f* __restrict__ ue4,
    const v4f* __restrict__ ie4,
    const v4f* __restrict__ noise_k, v4f* __restrict__ xnext,
    v4f* __restrict__ acc_out) {
    const int gl = threadIdx.x & 15;                 // lane within 16-lane row group
    const int r  = blockIdx.x * 16 + (threadIdx.x >> 4);
    if (r >= N_CNT) return;
    const int start = rowptr[r];
    const int end   = rowptr[r + 1];

    // hoisted single-use noise load (non-temporal; issues ~whole loop early)
    v4f nz = __builtin_nontemporal_load(&noise_k[(size_t)r * 16 + gl]);

    v4f acc = {0.f, 0.f, 0.f, 0.f};
    #pragma unroll 8
    for (int e = start; e < end; ++e) {
        unsigned long long pv = __builtin_nontemporal_load(
            (const unsigned long long*)(cpack + e));     // group-uniform 8B stream
        int   col = (int)(unsigned)(pv & 0xffffffffu);
        float vj  = __int_as_float((int)(unsigned)(pv >> 32));
        const v4f* xb;
        if (MODE == 0) {
            xb = (col < U_CNT) ? (ue4 + (size_t)col * 16)
                               : (ie4 + (size_t)(col - U_CNT) * 16);
        } else {
            xb = xin + (size_t)col * 16;
        }
        v4f xr = xb[gl];            // gather: normal load (wants L2 residency)
        acc += vj * xr;
    }

    // normalized noise (norm over the row's 64 features = 16 lanes x 4 comps)
    float sq = nz.x * nz.x + nz.y * nz.y + nz.z * nz.z + nz.w * nz.w;
    #pragma unroll
    for (int off = 8; off > 0; off >>= 1) sq += __shfl_xor(sq, off);
    float inv = EPS_F / fmaxf(sqrtf(sq), 1e-12f);

    v4f ego;
    ego.x = acc.x + sgnf(acc.x) * nz.x * inv;
    ego.y = acc.y + sgnf(acc.y) * nz.y * inv;
    ego.z = acc.z + sgnf(acc.z) * nz.z * inv;
    ego.w = acc.w + sgnf(acc.w) * nz.w * inv;

    size_t oi = (size_t)r * 16 + gl;
    if (MODE == 0) {
        xnext[oi] = ego;
        acc_out[oi] = ego;
    } else if (MODE == 1) {
        xnext[oi] = ego;
        v4f o = acc_out[oi];
        o += ego;
        acc_out[oi] = o;
    } else {
        v4f o = acc_out[oi];
        o = (o + ego) * (1.f / 3.f);
        acc_out[oi] = o;
    }
}

extern "C" void kernel_launch(void* const* d_in, const int* in_sizes, int n_in,
                              void* d_out, int out_size, void* d_ws, size_t ws_size,
                              hipStream_t stream) {
    const float* ue    = (const float*)d_in[0];
    const float* ie    = (const float*)d_in[1];
    const int*   rows  = (const int*)d_in[2];
    const int*   cols  = (const int*)d_in[3];
    const float* vals  = (const float*)d_in[4];
    const float* noise = (const float*)d_in[5];
    float* out = (float*)d_out;
    char*  ws  = (char*)d_ws;

    auto align16 = [](size_t x) { return (x + 15) & ~(size_t)15; };
    size_t off = 0;
    int*   rowptr   = (int*)(ws + off);  off = align16(off + (size_t)(N_CNT + 1) * 4);
    int*   deg      = (int*)(ws + off);  off = align16(off + (size_t)N_CNT * 4);
    int*   tileSums = (int*)(ws + off);  off = align16(off + (size_t)N_TILES * 4);
    int*   tileOffs = (int*)(ws + off);  off = align16(off + (size_t)N_TILES * 4);
    int2*  cpack    = (int2*)(ws + off); off = align16(off + (size_t)NNZ_CNT * 8);
    float* bufA     = (float*)(ws + off); off += (size_t)N_CNT * D_DIM * 4;
    (void)ws_size; (void)in_sizes; (void)n_in; (void)out_size;

    const size_t ND = (size_t)N_CNT * D_DIM;
    float* cl = out + ND;  // ego_cl region; doubles as layer-0 output / layer-1 input

    // ---- CSR build (round-0 proven form) ----
    hipMemsetAsync(deg, 0, (size_t)N_CNT * 4, stream);
    hist_kernel<<<(NNZ_CNT / 4 + 255) / 256, 256, 0, stream>>>(rows, deg);
    partial_scan_kernel<<<N_TILES, 256, 0, stream>>>(deg, rowptr, tileSums);  // zeroes deg
    scan_sums_kernel<<<1, 256, 0, stream>>>(tileSums, tileOffs, rowptr);
    add_offs_kernel<<<N_TILES, 256, 0, stream>>>(rowptr, tileOffs);
    scatter_kernel<<<(NNZ_CNT / 4 + 255) / 256, 256, 0, stream>>>(rows, cols, vals, rowptr,
                                                                  deg, cpack);

    // ---- 3 propagation layers (fused spmm + noise + accumulate) ----
    int blocks = (N_CNT + 15) / 16;
    layer_kernel<0><<<blocks, 256, 0, stream>>>(rowptr, cpack, nullptr,
                                                (const v4f*)ue, (const v4f*)ie,
                                                (const v4f*)(noise + 0 * ND),
                                                (v4f*)cl, (v4f*)out);
    layer_kernel<1><<<blocks, 256, 0, stream>>>(rowptr, cpack, (const v4f*)cl,
                                                nullptr, nullptr,
                                                (const v4f*)(noise + 1 * ND),
                                                (v4f*)bufA, (v4f*)out);
    layer_kernel<2><<<blocks, 256, 0, stream>>>(rowptr, cpack, (const v4f*)bufA,
                                                nullptr, nullptr,
                                                (const v4f*)(noise + 2 * ND),
                                                nullptr, (v4f*)out);
}

// Round 9
// 812.971 us; speedup vs baseline: 5.6227x; 1.3593x over previous
//
#include <hip/hip_runtime.h>
#include <cstdint>
#include <cstddef>

#define U_CNT 100000
#define I_CNT 50000
#define D_DIM 64
#define N_CNT (U_CNT + I_CNT)
#define NNZ_CNT 4000000
#define EPS_F 0.2f

// ---- bucket-sort CSR build geometry ----
#define BROWS 512                                   // rows per bucket (pow2: bucket = row>>9)
#define NBUCK ((N_CNT + BROWS - 1) / BROWS)         // 293
#define BCAP  16000                                 // staged cap/bucket (mean 13653, sigma~117 -> 20 sigma)
#define QUADS (NNZ_CNT / 4)                         // 1,000,000 int4-quads
#define QPB   4096                                  // quads per passA block (16384 edges)
#define GA    ((QUADS + QPB - 1) / QPB)             // 245 blocks
#define COL_MASK 0x3FFFF                            // col < 150000 < 2^18

// ---------------- passA: partition edges into row-buckets ----------------
// Per block: (1) LDS histogram of its 16K-edge tile over 293 buckets,
// (2) ONE global atomicAdd per (block,bucket) reserves a contiguous run,
// (3) re-walk tile, append (rl<<18|col, val) into the run. Runs are ~450B
// contiguous per block -> staged lines fill before writeback (no 8x amp).
__global__ __launch_bounds__(512) void passA_kernel(
    const int* __restrict__ rows, const int* __restrict__ cols,
    const float* __restrict__ vals, int* __restrict__ gcur,
    int2* __restrict__ staged) {
    __shared__ int lcnt[NBUCK];
    __shared__ int goff[NBUCK];
    __shared__ int lcur[NBUCK];
    const int t = threadIdx.x;
    for (int i = t; i < NBUCK; i += 512) { lcnt[i] = 0; lcur[i] = 0; }
    __syncthreads();
    const int qbase = blockIdx.x * QPB;
    // phase 1: tile histogram
    #pragma unroll
    for (int k = 0; k < QPB / 512; ++k) {
        int q = qbase + t + k * 512;
        if (q < QUADS) {
            int4 r4 = ((const int4*)rows)[q];
            atomicAdd(&lcnt[r4.x >> 9], 1);
            atomicAdd(&lcnt[r4.y >> 9], 1);
            atomicAdd(&lcnt[r4.z >> 9], 1);
            atomicAdd(&lcnt[r4.w >> 9], 1);
        }
    }
    __syncthreads();
    // reserve per-bucket runs (75K atomics total across the grid)
    for (int b = t; b < NBUCK; b += 512)
        goff[b] = (lcnt[b] > 0) ? atomicAdd(&gcur[b], lcnt[b]) : 0;
    __syncthreads();
    // phase 2: append into reserved runs
    #pragma unroll
    for (int k = 0; k < QPB / 512; ++k) {
        int q = qbase + t + k * 512;
        if (q < QUADS) {
            int4   r4 = ((const int4*)rows)[q];
            int4   c4 = ((const int4*)cols)[q];
            float4 v4 = ((const float4*)vals)[q];
            int b, p;
            b = r4.x >> 9; p = atomicAdd(&lcur[b], 1);
            staged[(size_t)b * BCAP + goff[b] + p] =
                make_int2(((r4.x & 511) << 18) | c4.x, __float_as_int(v4.x));
            b = r4.y >> 9; p = atomicAdd(&lcur[b], 1);
            staged[(size_t)b * BCAP + goff[b] + p] =
                make_int2(((r4.y & 511) << 18) | c4.y, __float_as_int(v4.y));
            b = r4.z >> 9; p = atomicAdd(&lcur[b], 1);
            staged[(size_t)b * BCAP + goff[b] + p] =
                make_int2(((r4.z & 511) << 18) | c4.z, __float_as_int(v4.z));
            b = r4.w >> 9; p = atomicAdd(&lcur[b], 1);
            staged[(size_t)b * BCAP + goff[b] + p] =
                make_int2(((r4.w & 511) << 18) | c4.w, __float_as_int(v4.w));
        }
    }
}

// ---------------- scanB: bucket sizes -> cpack bases (293 <= 512) ----------
__global__ __launch_bounds__(512) void scanB_kernel(
    const int* __restrict__ gcur, int* __restrict__ cbase,
    int* __restrict__ rowptr) {
    __shared__ int lds[512];
    const int t = threadIdx.x;
    lds[t] = (t < NBUCK) ? gcur[t] : 0;
    __syncthreads();
    for (int off = 1; off < 512; off <<= 1) {
        int x = (t >= off) ? lds[t - off] : 0;
        __syncthreads();
        lds[t] += x;
        __syncthreads();
    }
    if (t < NBUCK) cbase[t] = (t > 0) ? lds[t - 1] : 0;
    if (t == 0) rowptr[N_CNT] = NNZ_CNT;
}

// ---------------- passB: per-bucket rowptr + final cpack ----------------
// One block OWNS one bucket: its cpack slice (~110KB) is written only by this
// block -> lines live in one XCD's L2 and fill completely before writeback
// (cpack write = 32MB total, vs 247MB for the old device-wide scatter).
__global__ __launch_bounds__(512) void passB_kernel(
    const int2* __restrict__ staged, const int* __restrict__ gcur,
    const int* __restrict__ cbase, int* __restrict__ rowptr,
    int2* __restrict__ cpack) {
    __shared__ int cnt[BROWS];
    __shared__ int cur[BROWS];
    const int b = blockIdx.x;
    const int t = threadIdx.x;
    const int nE = gcur[b];
    const int base = cbase[b];
    const int row0 = b * BROWS;
    const int rowsIn = (N_CNT - row0 < BROWS) ? (N_CNT - row0) : BROWS;
    const int2* sb = staged + (size_t)b * BCAP;
    cnt[t] = 0;
    __syncthreads();
    for (int e = t; e < nE; e += 512)
        atomicAdd(&cnt[((unsigned)sb[e].x) >> 18], 1);
    __syncthreads();
    // inclusive scan over 512 row counts
    for (int off = 1; off < 512; off <<= 1) {
        int x = (t >= off) ? cnt[t - off] : 0;
        __syncthreads();
        cnt[t] += x;
        __syncthreads();
    }
    int excl = (t > 0) ? cnt[t - 1] : 0;
    cur[t] = excl;
    if (t < rowsIn) rowptr[row0 + t] = base + excl;
    __syncthreads();
    for (int e = t; e < nE; e += 512) {
        int2 pk = sb[e];
        int rl = ((unsigned)pk.x) >> 18;
        int p = atomicAdd(&cur[rl], 1);
        cpack[base + p] = make_int2(pk.x & COL_MASK, pk.y);
    }
}

__device__ __forceinline__ float sgnf(float x) {
    return (x > 0.f) ? 1.f : ((x < 0.f) ? -1.f : 0.f);
}

// ---------------- fused SpMM + noise + accumulate (round-0 proven form) ------
// 16 lanes per row (each lane owns a float4 of D=64); 4 rows per wave,
// 16 rows per 256-thread block. Edge metadata read group-uniformly (no shfl).
// MODE 0: gather from (ue,ie) split; xnext = ego; acc_out = ego   (layer 0)
// MODE 1: gather from xin;          xnext = ego; acc_out += ego   (layer 1)
// MODE 2: gather from xin;          acc_out = (acc_out + ego)/3   (layer 2)
template <int MODE>
__global__ __launch_bounds__(256) void layer_kernel(
    const int* __restrict__ rowptr, const int2* __restrict__ cpack,
    const float4* __restrict__ xin, const float4* __restrict__ ue4,
    const float4* __restrict__ ie4,
    const float4* __restrict__ noise_k, float4* __restrict__ xnext,
    float4* __restrict__ acc_out) {
    const int gl = threadIdx.x & 15;                 // lane within 16-lane row group
    const int r  = blockIdx.x * 16 + (threadIdx.x >> 4);
    if (r >= N_CNT) return;
    const int start = rowptr[r];
    const int end   = rowptr[r + 1];

    float4 acc = make_float4(0.f, 0.f, 0.f, 0.f);
    #pragma unroll 4
    for (int e = start; e < end; ++e) {
        int2 p = cpack[e];                            // group-uniform 8B load
        float vj = __int_as_float(p.y);
        const float4* xb;
        if (MODE == 0) {
            xb = (p.x < U_CNT) ? (ue4 + (size_t)p.x * 16)
                               : (ie4 + (size_t)(p.x - U_CNT) * 16);
        } else {
            xb = xin + (size_t)p.x * 16;
        }
        float4 xr = xb[gl];                           // 256B/row, coalesced over 16 lanes
        acc.x += vj * xr.x;
        acc.y += vj * xr.y;
        acc.z += vj * xr.z;
        acc.w += vj * xr.w;
    }

    // normalized noise (norm over the row's 64 features = 16 lanes x 4 comps)
    float4 nz = noise_k[(size_t)r * 16 + gl];
    float sq = nz.x * nz.x + nz.y * nz.y + nz.z * nz.z + nz.w * nz.w;
    #pragma unroll
    for (int off = 8; off > 0; off >>= 1) sq += __shfl_xor(sq, off);
    float inv = EPS_F / fmaxf(sqrtf(sq), 1e-12f);

    float4 ego;
    ego.x = acc.x + sgnf(acc.x) * nz.x * inv;
    ego.y = acc.y + sgnf(acc.y) * nz.y * inv;
    ego.z = acc.z + sgnf(acc.z) * nz.z * inv;
    ego.w = acc.w + sgnf(acc.w) * nz.w * inv;

    size_t oi = (size_t)r * 16 + gl;
    if (MODE == 0) {
        xnext[oi] = ego;
        acc_out[oi] = ego;
    } else if (MODE == 1) {
        xnext[oi] = ego;
        float4 a = acc_out[oi];
        a.x += ego.x; a.y += ego.y; a.z += ego.z; a.w += ego.w;
        acc_out[oi] = a;
    } else {
        float4 a = acc_out[oi];
        a.x = (a.x + ego.x) * (1.f / 3.f);
        a.y = (a.y + ego.y) * (1.f / 3.f);
        a.z = (a.z + ego.z) * (1.f / 3.f);
        a.w = (a.w + ego.w) * (1.f / 3.f);
        acc_out[oi] = a;
    }
}

extern "C" void kernel_launch(void* const* d_in, const int* in_sizes, int n_in,
                              void* d_out, int out_size, void* d_ws, size_t ws_size,
                              hipStream_t stream) {
    const float* ue    = (const float*)d_in[0];
    const float* ie    = (const float*)d_in[1];
    const int*   rows  = (const int*)d_in[2];
    const int*   cols  = (const int*)d_in[3];
    const float* vals  = (const float*)d_in[4];
    const float* noise = (const float*)d_in[5];
    float* out = (float*)d_out;
    char*  ws  = (char*)d_ws;

    auto align16 = [](size_t x) { return (x + 15) & ~(size_t)15; };
    size_t off = 0;
    int*   rowptr = (int*)(ws + off);  off = align16(off + (size_t)(N_CNT + 1) * 4);
    int*   gcur   = (int*)(ws + off);  off = align16(off + (size_t)NBUCK * 4);
    int*   cbase  = (int*)(ws + off);  off = align16(off + (size_t)NBUCK * 4);
    int2*  cpack  = (int2*)(ws + off); off = align16(off + (size_t)NNZ_CNT * 8);
    float* bufA   = (float*)(ws + off); off += (size_t)N_CNT * D_DIM * 4;
    // staged (293*16000*8 = 37.5MB) aliases bufA (38.4MB): staged is dead
    // before layer 1 writes bufA.
    int2*  staged = (int2*)bufA;
    (void)ws_size; (void)in_sizes; (void)n_in; (void)out_size;

    const size_t ND = (size_t)N_CNT * D_DIM;
    float* cl = out + ND;  // ego_cl region; doubles as layer-0 output / layer-1 input

    // ---- CSR build: two-pass bucket sort (replaces hist/scan/scatter) ----
    hipMemsetAsync(gcur, 0, (size_t)NBUCK * 4, stream);
    passA_kernel<<<GA, 512, 0, stream>>>(rows, cols, vals, gcur, staged);
    scanB_kernel<<<1, 512, 0, stream>>>(gcur, cbase, rowptr);
    passB_kernel<<<NBUCK, 512, 0, stream>>>(staged, gcur, cbase, rowptr, cpack);

    // ---- 3 propagation layers (round-0 proven form) ----
    int blocks = (N_CNT + 15) / 16;
    layer_kernel<0><<<blocks, 256, 0, stream>>>(rowptr, cpack, nullptr,
                                                (const float4*)ue, (const float4*)ie,
                                                (const float4*)(noise + 0 * ND),
                                                (float4*)cl, (float4*)out);
    layer_kernel<1><<<blocks, 256, 0, stream>>>(rowptr, cpack, (const float4*)cl,
                                                nullptr, nullptr,
                                                (const float4*)(noise + 1 * ND),
                                                (float4*)bufA, (float4*)out);
    layer_kernel<2><<<blocks, 256, 0, stream>>>(rowptr, cpack, (const float4*)bufA,
                                                nullptr, nullptr,
                                                (const float4*)(noise + 2 * ND),
                                                nullptr, (float4*)out);
}